// Round 9
// baseline (734.554 us; speedup 1.0000x reference)
//
#include <hip/hip_runtime.h>
#include <hip/hip_fp16.h>

// GRU cell, B=65536, 256 inputs, 256 hidden, fp32 in/out.
// R13: persistent single-generation pipeline, R9's idea with R9's flaw fixed.
// Evidence: all clean structures (R5/R8/R10/R11) land 133-150us while pipe
// busy-time sums to only ~75us (MFMA 21 + HBM 35 + VALU ~17). Falsified:
// prefetch depth, vmcnt drains, block desync (R8), TLP 2x (R11: 8w/SIMD
// clean, -12%), epi-fusion (R10), reg-payload persistence (R9: 64 VGPR of
// staged float4 -> cap/spills). Invariant left: 2 dispatch generations whose
// stage-in (~64MB) and write-out (~64MB) phases are chip-synchronized bursts
// that never overlap compute. Fix: 512 persistent blocks (exactly 2/CU by
// 64KB LDS), 4 tiles each, double-buffered LDS tile (2 x (lx+lh) fp16);
// tile t+1's x staged at ~1 float4/thread per pass-1 step (issue even-s,
// consume odd-s: 1 transient float4 in flight, not R9's 16), h staged in
// pass-2 s=0..8. All cross-tile LDS hazards separated by the EXISTING lgkm
// barriers: x-writes vs t-1's lx reads by t-1's pass2-s8 barrier; h-writes
// vs t-1's lh reads by t's pre-epi1 barrier; visibility to t+1 by t's
// pass2-s8 barrier (h chunk 7 consumed just before it). Epi2 stores overlap
// next tile's pass1 (no trailing barrier, lgkm-only barriers keep stores in
// flight). Only tile0 staging + last write-out exposed.
// Retained from R8 (best): 4 waves, CPW=4, RT=2, coltile-pair micro-step
// weight dbuf, lgkm-only barriers, s==8 movable barrier, NT stores, setprio,
// __launch_bounds__(256,2) -> VGPR cap 128 (measured rule).

#define NHID 256
#define B_ROWS 65536
#define MT 32                        // rows per tile
#define RT 2                         // row tiles per wave (MT/16)
#define CPW 4                        // coltiles per wave (16 coltiles / 4 waves)
#define TPB 4                        // tiles per persistent block
#define NBLK 512                     // 2 blocks/CU -> single generation
#define TILEH (MT * 256)             // halves per x (or h) tile buffer
#define GATE_STRIDE (16 * 16 * 64 * 8)   // halves per packed gate

typedef _Float16 half8 __attribute__((ext_vector_type(8)));
typedef _Float16 half4_t __attribute__((ext_vector_type(4)));
typedef _Float16 half2_t __attribute__((ext_vector_type(2)));
typedef float floatx4 __attribute__((ext_vector_type(4)));

// LDS layout for lx/lh: row-major [MT][256] halves, 8-half-chunk XOR swizzle
__device__ __forceinline__ int lidx(int m, int c) {
    return m * 256 + ((((c >> 3) ^ (m & 7)) << 3)) + (c & 7);
}

// Workgroup barrier that waits only on LDS ops (lgkmcnt), NOT vmcnt -- keeps
// prefetched global loads and NT stores in flight across phase boundaries.
__device__ __forceinline__ void barrier_lgkm() {
    __builtin_amdgcn_sched_barrier(0);
    asm volatile("s_waitcnt lgkmcnt(0)" ::: "memory");
    __builtin_amdgcn_s_barrier();
    __builtin_amdgcn_sched_barrier(0);
}

// ---------- weight packing: B-fragment layout for mfma_f32_16x16x32_f16 ----
// frag (gate g, coltile ct, ktile s): lane holds B[k=s*32+(lane>>4)*8+j][n=ct*16+(lane&15)]
__global__ __launch_bounds__(256) void pack_weights_kernel(
    const float* __restrict__ Wz, const float* __restrict__ Uz,
    const float* __restrict__ Wr, const float* __restrict__ Ur,
    const float* __restrict__ Wh, const float* __restrict__ Uh,
    _Float16* __restrict__ packed)
{
    int tid = blockIdx.x * blockDim.x + threadIdx.x;  // 0..49151
    int lane = tid & 63;
    int s    = (tid >> 6) & 15;
    int ct   = (tid >> 10) & 15;
    int g    = tid >> 14;  // 0:z 1:r 2:h
    const float* W = (g == 0) ? Wz : (g == 1) ? Wr : Wh;
    const float* U = (g == 0) ? Uz : (g == 1) ? Ur : Uh;
    int n  = ct * 16 + (lane & 15);
    int k0 = s * 32 + (lane >> 4) * 8;
    half8 v;
#pragma unroll
    for (int j = 0; j < 8; ++j) {
        int k = k0 + j;
        float f = (k < 256) ? W[k * 256 + n] : U[(k - 256) * 256 + n];
        v[j] = (_Float16)f;
    }
    *reinterpret_cast<half8*>(packed + (size_t)tid * 8) = v;
}

// fragment load for (gate base, coltile ct, ktile s)
#define WFRAG(base, ct, s) \
    (*reinterpret_cast<const half8*>((base) + (size_t)((((ct) * 16 + (s)) * 64 + lane) * 8)))

// ---------- main fused GRU kernel ----------
__global__ __launch_bounds__(256, 2) void gru_main_kernel(
    const float* __restrict__ x, const float* __restrict__ h,
    const _Float16* __restrict__ wpack,
    const float* __restrict__ bz, const float* __restrict__ br,
    const float* __restrict__ bh,
    float* __restrict__ out)
{
    // 64 KB: [buf][x|h] double-buffered fp16 tiles -> 2 blocks/CU (128/160KB)
    __shared__ __align__(16) _Float16 lsm[4 * TILEH];

    const int tid   = threadIdx.x;
    const int lane  = tid & 63;
    const int wave  = tid >> 6;       // 0..3, owns coltiles wave*4..wave*4+3
    const int m_lo  = lane & 15;
    const int quad  = lane >> 4;
    const int mx    = m_lo & 7;
    const int ct0   = wave * CPW;
    const int lane4 = lane * 4;       // staging column

    const _Float16* wz = wpack;
    const _Float16* wr = wpack + GATE_STRIDE;
    const _Float16* wh = wpack + 2 * GATE_STRIDE;
    const float4* xv4 = reinterpret_cast<const float4*>(x);
    const float4* hv4 = reinterpret_cast<const float4*>(h);
    const size_t OUT2 = (size_t)B_ROWS * NHID;

    // staging write of one float4 as fp16 into row m = j*4+wave, col lane*4
    auto stage_wr = [&](_Float16* dst, const float4& v, int j) {
        const int m = j * 4 + wave;
        half4_t p = { (_Float16)v.x, (_Float16)v.y, (_Float16)v.z, (_Float16)v.w };
        *reinterpret_cast<half4_t*>(&dst[lidx(m, lane4)]) = p;
    };

    // biases: once for all tiles
    float bzv[CPW], brv[CPW], bhv[CPW];
#pragma unroll
    for (int c = 0; c < CPW; ++c) {
        const int col = (ct0 + c) * 16 + m_lo;
        bzv[c] = bz[col];
        brv[c] = br[col];
        bhv[c] = bh[col];
    }

    // pass-1 step-0 weight frags: fly under prologue staging
    half8 wzb[2][2], wrb[2][2];
    wzb[0][0] = WFRAG(wz, ct0 + 0, 0);
    wzb[0][1] = WFRAG(wz, ct0 + 1, 0);
    wrb[0][0] = WFRAG(wr, ct0 + 0, 0);
    wrb[0][1] = WFRAG(wr, ct0 + 1, 0);

    // ---- prologue: stage tile 0 (the only fully exposed staging) ----
    {
        const size_t ib = (size_t)(blockIdx.x * TPB * MT) * 64 + tid;
#pragma unroll
        for (int j = 0; j < 8; ++j) {
            float4 a = xv4[ib + j * 256];
            float4 b = hv4[ib + j * 256];
            stage_wr(lsm, a, j);             // buf0 lx
            stage_wr(lsm + TILEH, b, j);     // buf0 lh
        }
    }
    barrier_lgkm();

#pragma unroll 1
    for (int t = 0; t < TPB; ++t) {
        const int buf = t & 1;
        _Float16* lxc = lsm + buf * (2 * TILEH);
        _Float16* lhc = lxc + TILEH;
        _Float16* lxn = lsm + (buf ^ 1) * (2 * TILEH);
        _Float16* lhn = lxn + TILEH;
        const int row0 = (blockIdx.x * TPB + t) * MT;
        const size_t nib = (size_t)(row0 + MT) * 64 + tid;  // next tile base
        const bool more = (t < TPB - 1);

        half2_t zpk[CPW][RT][4];

        // ---- pass 1: Sz, Sr (K=512); x-staging for t+1 interleaved ----
        floatx4 accz[CPW][RT];
        floatx4 accr[CPW][RT];
#pragma unroll
        for (int c = 0; c < CPW; ++c)
#pragma unroll
            for (int rt = 0; rt < RT; ++rt) {
                accz[c][rt] = (floatx4){0.f, 0.f, 0.f, 0.f};
                accr[c][rt] = (floatx4){0.f, 0.f, 0.f, 0.f};
            }

        float4 xin;
#pragma unroll
        for (int s = 0; s < 16; ++s) {
            if (more) {
                if ((s & 1) == 0) xin = xv4[nib + (s >> 1) * 256]; // issue j
                else              stage_wr(lxn, xin, s >> 1);      // consume j
            }
            const _Float16* asrc = (s < 8) ? lxc : lhc;
            const int kcx = (((s & 7) * 4 + quad) ^ mx) << 3;
            half8 af[RT];
#pragma unroll
            for (int rt = 0; rt < RT; ++rt)
                af[rt] = *reinterpret_cast<const half8*>(&asrc[(rt * 16 + m_lo) * 256 + kcx]);
#pragma unroll
            for (int p = 0; p < 2; ++p) {
                const int u = s * 2 + p;
                if (u < 31) {
                    const int ns = (p == 1) ? s + 1 : s;
                    const int nc = ct0 + (p ^ 1) * 2;
                    wzb[p ^ 1][0] = WFRAG(wz, nc + 0, ns);
                    wzb[p ^ 1][1] = WFRAG(wz, nc + 1, ns);
                    wrb[p ^ 1][0] = WFRAG(wr, nc + 0, ns);
                    wrb[p ^ 1][1] = WFRAG(wr, nc + 1, ns);
                }
                __builtin_amdgcn_s_setprio(1);
#pragma unroll
                for (int q = 0; q < 2; ++q) {
                    const int c = p * 2 + q;
#pragma unroll
                    for (int rt = 0; rt < RT; ++rt) {
                        accz[c][rt] = __builtin_amdgcn_mfma_f32_16x16x32_f16(af[rt], wzb[p][q], accz[c][rt], 0, 0, 0);
                        accr[c][rt] = __builtin_amdgcn_mfma_f32_16x16x32_f16(af[rt], wrb[p][q], accr[c][rt], 0, 0, 0);
                    }
                }
                __builtin_amdgcn_s_setprio(0);
            }
        }

        // pass-2 step-0 weights: in flight through epilogue 1
        half8 whb[2][2];
        whb[0][0] = WFRAG(wh, ct0 + 0, 0);
        whb[0][1] = WFRAG(wh, ct0 + 1, 0);

        barrier_lgkm();  // all waves done with lhc (pass1) AND tile t-1 fully

        // ---- epilogue 1: z, r; lhc <- r*h; zpk <- (fp16)(z*h, 1-z) ----
        // C layout: col(tile) = lane&15, row(tile) = quad*4 + reg
#pragma unroll
        for (int c = 0; c < CPW; ++c) {
            const int col = (ct0 + c) * 16 + m_lo;
#pragma unroll
            for (int rt = 0; rt < RT; ++rt) {
#pragma unroll
                for (int e = 0; e < 4; ++e) {
                    const int row = rt * 16 + quad * 4 + e;
                    float sz = accz[c][rt][e] + bzv[c];
                    float sr = accr[c][rt][e] + brv[c];
                    float zv = 1.f / (1.f + __expf(-sz));
                    float rv = 1.f / (1.f + __expf(-sr));
                    const int li = lidx(row, col);
                    float hval = (float)lhc[li];
                    lhc[li] = (_Float16)(rv * hval);
                    zpk[c][rt][e] = half2_t{ (_Float16)(zv * hval), (_Float16)(1.f - zv) };
                }
            }
        }
        // NO barrier: pass-2 s<8 reads only lxc; lhc barrier is at s==8.

        // ---- pass 2: Sh (K=512); h-staging for t+1 in s=0..8 ----
        floatx4 acch[CPW][RT];
#pragma unroll
        for (int c = 0; c < CPW; ++c)
#pragma unroll
            for (int rt = 0; rt < RT; ++rt)
                acch[c][rt] = (floatx4){0.f, 0.f, 0.f, 0.f};

        float4 hin[2];
#pragma unroll
        for (int s = 0; s < 16; ++s) {
            if (more) {
                if (s >= 1 && s <= 8) stage_wr(lhn, hin[(s - 1) & 1], s - 1);
                if (s < 8) hin[s & 1] = hv4[nib + s * 256];
            }
            if (s == 8) barrier_lgkm();  // r*h visible; h-staging drained
            const _Float16* asrc = (s < 8) ? lxc : lhc;
            const int kcx = (((s & 7) * 4 + quad) ^ mx) << 3;
            half8 af[RT];
#pragma unroll
            for (int rt = 0; rt < RT; ++rt)
                af[rt] = *reinterpret_cast<const half8*>(&asrc[(rt * 16 + m_lo) * 256 + kcx]);
#pragma unroll
            for (int p = 0; p < 2; ++p) {
                const int u = s * 2 + p;
                if (u < 31) {
                    const int ns = (p == 1) ? s + 1 : s;
                    const int nc = ct0 + (p ^ 1) * 2;
                    whb[p ^ 1][0] = WFRAG(wh, nc + 0, ns);
                    whb[p ^ 1][1] = WFRAG(wh, nc + 1, ns);
                }
                __builtin_amdgcn_s_setprio(1);
#pragma unroll
                for (int q = 0; q < 2; ++q) {
                    const int c = p * 2 + q;
#pragma unroll
                    for (int rt = 0; rt < RT; ++rt)
                        acch[c][rt] = __builtin_amdgcn_mfma_f32_16x16x32_f16(af[rt], whb[p][q], acch[c][rt], 0, 0, 0);
                }
                __builtin_amdgcn_s_setprio(0);
            }
        }

        // next tile's pass-1 step-0 weights: fly under epilogue 2
        if (more) {
            wzb[0][0] = WFRAG(wz, ct0 + 0, 0);
            wzb[0][1] = WFRAG(wz, ct0 + 1, 0);
            wrb[0][0] = WFRAG(wr, ct0 + 0, 0);
            wrb[0][1] = WFRAG(wr, ct0 + 1, 0);
        }

        // ---- epilogue 2: h_t = z*h + (1-z)*tanh(Sh+bh); NT stores overlap
        //      the next tile's pass 1 (no trailing barrier, no vmcnt drain).
#pragma unroll
        for (int c = 0; c < CPW; ++c) {
            const int col = (ct0 + c) * 16 + m_lo;
#pragma unroll
            for (int rt = 0; rt < RT; ++rt) {
#pragma unroll
                for (int e = 0; e < 4; ++e) {
                    const int row = rt * 16 + quad * 4 + e;
                    float sh = acch[c][rt][e] + bhv[c];
                    float e2 = __expf(2.f * sh);
                    float hh = 1.f - 2.f / (e2 + 1.f);  // tanh
                    float zh  = (float)zpk[c][rt][e][0];
                    float omz = (float)zpk[c][rt][e][1];
                    float ht  = zh + omz * hh;
                    size_t idx = (size_t)(row0 + row) * NHID + col;
                    __builtin_nontemporal_store(ht, &out[idx]);
                    __builtin_nontemporal_store(ht, &out[OUT2 + idx]);
                }
            }
        }
    }
}

extern "C" void kernel_launch(void* const* d_in, const int* in_sizes, int n_in,
                              void* d_out, int out_size, void* d_ws, size_t ws_size,
                              hipStream_t stream) {
    (void)in_sizes; (void)n_in; (void)out_size; (void)ws_size;
    const float* x  = (const float*)d_in[0];
    const float* h  = (const float*)d_in[1];
    const float* Wz = (const float*)d_in[2];
    const float* Uz = (const float*)d_in[3];
    const float* bz = (const float*)d_in[4];
    const float* Wr = (const float*)d_in[5];
    const float* Ur = (const float*)d_in[6];
    const float* br = (const float*)d_in[7];
    const float* Wh = (const float*)d_in[8];
    const float* Uh = (const float*)d_in[9];
    const float* bh = (const float*)d_in[10];
    float* out = (float*)d_out;
    _Float16* wpack = (_Float16*)d_ws;  // 3*512*256*2 = 768 KB

    pack_weights_kernel<<<192, 256, 0, stream>>>(Wz, Uz, Wr, Ur, Wh, Uh, wpack);
    gru_main_kernel<<<NBLK, 256, 0, stream>>>(x, h, wpack, bz, br, bh, out);
}